// Round 4
// baseline (164.512 us; speedup 1.0000x reference)
//
#include <hip/hip_runtime.h>
#include <math.h>

// Problem constants
#define BS    2048            // batch
#define NROW  4096            // B*V = N
#define EDIM  256
#define INVT  (1.0f/0.07f)

typedef float  float4v __attribute__((ext_vector_type(4)));
typedef short  short8v __attribute__((ext_vector_type(8)));

static __device__ __forceinline__ unsigned short f2bf(float x) {
    // round-to-nearest-even f32 -> bf16 (inputs are finite)
    unsigned u = __builtin_bit_cast(unsigned, x);
    u += 0x7fffu + ((u >> 16) & 1u);
    return (unsigned short)(u >> 16);
}

static __device__ __forceinline__ float agent_load(const float* p) {
    return __hip_atomic_load(p, __ATOMIC_RELAXED, __HIP_MEMORY_SCOPE_AGENT);
}

// ---------------- prep kernel: normalize + label bits + zero accumulators ----
// blocks 0..4095: row normalize (wave w = head w); blocks 4096..4103: labels + zeroing
__global__ void prep_kernel(const float* __restrict__ feat, const float* __restrict__ labels,
                            unsigned short* __restrict__ fnb, unsigned* __restrict__ bits,
                            float* __restrict__ zacc) {
    const int b = blockIdx.x, t = threadIdx.x;
    if (b < NROW) {
        int bb = b & (BS - 1);
        int v = b >> 11;
        float x = feat[(size_t)bb * (2 * EDIM) + (size_t)v * EDIM + t];
        float ss = x * x;
#pragma unroll
        for (int off = 32; off > 0; off >>= 1)
            ss += __shfl_xor(ss, off, 64);
        float nrm = fmaxf(sqrtf(ss), 1e-12f);
        fnb[(size_t)b * EDIM + t] = f2bf(x / nrm);
    } else {
        int g = (b - NROW) * 256 + t;   // 0..2047
        unsigned bb = 0;
#pragma unroll
        for (int d = 0; d < 10; ++d)
            bb |= (labels[g * 10 + d] != 0.0f ? 1u : 0u) << d;
        bits[g] = bb;
        // zero S (N*4), Num (N), Cnt (N*4), red[2], done[1], cnt_bx[128]
        for (int k = g; k < NROW * 9 + 131; k += 2048) zacc[k] = 0.0f;
    }
}

// ---------------- main kernel (bf16 MFMA, register-resident B, no LDS) ------
// grid (128 i-groups, 8 j-chunks), block 128 = 2 waves, all 1024 blocks
// co-resident (6 blocks/CU fit at 3 waves/EU; 4 needed).
// Wave w: i-rows [bx*32 + w*16, +16), j-chunk [by*512, +512) as 8 tiles of 64.
// A fragments hoisted to regs; B fragments loaded per-tile straight from
// global (fnb = 2 MB, resident in every XCD L2).  NO __syncthreads in the
// compute loop -> no vmcnt(0) barrier drains; compiler pipelines freely.
// C/D layout (m89/m91): col = lane&15, row = (lane>>4)*4 + reg.
// A/B operand layout: lane l -> m/n = l&15, k = (l>>4)*8 + [0..8).
// After the j-loop each block flushes per-row partials with device atomics;
// the 8th (last) contributor per i-group finalizes its 32 rows; the 128th
// finalizer writes out[0].
__global__ __launch_bounds__(128, 3) void main_kernel(
    const unsigned short* __restrict__ fnb, const unsigned* __restrict__ bits,
    float* __restrict__ S, float* __restrict__ Num, float* __restrict__ Cnt,
    float* __restrict__ red, unsigned* __restrict__ done,
    unsigned* __restrict__ cnt_bx, float* __restrict__ out) {

    const int tid  = threadIdx.x;
    const int lane = tid & 63;
    const int wave = tid >> 6;
    const int quad = lane >> 4;
    const int ml   = lane & 15;
    const int bx   = blockIdx.x;
    const int i0   = bx * 32 + wave * 16;
    const int jc0  = blockIdx.y * 512;

    // A fragments: af[h][kk], 8 x short8 = 32 VGPRs (rows i0..i0+15)
    short8v af[4][2];
    {
        const unsigned short* ap = fnb + (size_t)(i0 + ml) * EDIM + quad * 8;
#pragma unroll
        for (int h = 0; h < 4; ++h)
#pragma unroll
            for (int kk = 0; kk < 2; ++kk)
                af[h][kk] = *(const short8v*)(ap + h * 64 + kk * 32);
    }

    unsigned ibr[4];
#pragma unroll
    for (int r = 0; r < 4; ++r)
        ibr[r] = bits[(i0 + quad * 4 + r) & (BS - 1)];

    float    Sp[4][4] = {};
    float    np[4] = {};
    unsigned cpk[4] = {};   // per row: 4 x 8-bit argmax-head counts

    for (int t = 0; t < 8; ++t) {
        const int j0 = jc0 + t * 64;

        unsigned jbr[4];
#pragma unroll
        for (int js = 0; js < 4; ++js)
            jbr[js] = bits[(j0 + js * 16 + ml) & (BS - 1)];

        float4v dacc[4][4];   // [js][h]
#pragma unroll
        for (int js = 0; js < 4; ++js)
#pragma unroll
            for (int h = 0; h < 4; ++h)
                dacc[js][h] = (float4v){0.f, 0.f, 0.f, 0.f};

        // B fragments straight from global (L2-hit), no LDS, no barriers
#pragma unroll
        for (int h = 0; h < 4; ++h)
#pragma unroll
            for (int kk = 0; kk < 2; ++kk) {
                const int ko = h * 64 + kk * 32 + quad * 8;
                short8v bf[4];
#pragma unroll
                for (int js = 0; js < 4; ++js)
                    bf[js] = *(const short8v*)(fnb + (size_t)(j0 + js * 16 + ml) * EDIM + ko);
#pragma unroll
                for (int js = 0; js < 4; ++js)
                    dacc[js][h] = __builtin_amdgcn_mfma_f32_16x16x32_bf16(af[h][kk], bf[js], dacc[js][h], 0, 0, 0);
            }

        // epilogue: 16 (i,j) pairs per lane, 4 heads each
#pragma unroll
        for (int r = 0; r < 4; ++r) {
            const int i = i0 + quad * 4 + r;
            const unsigned ibit = ibr[r];
#pragma unroll
            for (int js = 0; js < 4; ++js) {
                const int j = j0 + js * 16 + ml;
                const float d0 = dacc[js][0][r];
                const float d1 = dacc[js][1][r];
                const float d2 = dacc[js][2][r];
                const float d3 = dacc[js][3][r];
                // argmax, first index wins ties
                float bd = d0; int bh = 0;
                if (d1 > bd) { bd = d1; bh = 1; }
                if (d2 > bd) { bd = d2; bh = 2; }
                if (d3 > bd) { bd = d3; bh = 3; }
                const bool off = (i != j);
                const float e0 = __expf(fmaf(d0, INVT, -INVT));
                const float e1 = __expf(fmaf(d1, INVT, -INVT));
                const float e2 = __expf(fmaf(d2, INVT, -INVT));
                const float e3 = __expf(fmaf(d3, INVT, -INVT));
                if (off) {
                    Sp[r][0] += e0; Sp[r][1] += e1; Sp[r][2] += e2; Sp[r][3] += e3;
                }
                if (off && (ibit & jbr[js])) {
                    np[r] += bd;              // raw dot; * INVT at flush
                    cpk[r] += 1u << (bh * 8);
                }
            }
        }
    }

    // reduce the 16 lanes sharing each row, then one global atomic per value
#pragma unroll
    for (int r = 0; r < 4; ++r) {
        const int i = i0 + quad * 4 + r;
        float v[9];
        v[0] = np[r];
#pragma unroll
        for (int h = 0; h < 4; ++h) v[1 + h] = Sp[r][h];
#pragma unroll
        for (int h = 0; h < 4; ++h) v[5 + h] = (float)((cpk[r] >> (8 * h)) & 255u);
#pragma unroll
        for (int k = 0; k < 9; ++k) {
            float x = v[k];
            x += __shfl_xor(x, 1, 64);
            x += __shfl_xor(x, 2, 64);
            x += __shfl_xor(x, 4, 64);
            x += __shfl_xor(x, 8, 64);
            v[k] = x;
        }
        if (ml == 0) {
            atomicAdd(&Num[i], v[0] * INVT);
#pragma unroll
            for (int h = 0; h < 4; ++h) atomicAdd(&S[i * 4 + h], v[1 + h]);
#pragma unroll
            for (int h = 0; h < 4; ++h) atomicAdd(&Cnt[i * 4 + h], v[5 + h]);
        }
    }

    // ---- in-kernel finalization: last j-chunk contributor per i-group ----
    __shared__ unsigned flag;
    __threadfence();
    __syncthreads();                 // both waves' flush atomics issued
    if (tid == 0) flag = atomicAdd(&cnt_bx[bx], 1u);
    __syncthreads();
    if (flag == 7u && tid < 64) {    // wave 0 finalizes rows [bx*32, +32)
        float ls = 0.f, lc = 0.f;
        if (tid < 32) {
            const int i = bx * 32 + tid;
            float c = 0.f;
            float numr = agent_load(&Num[i]);
#pragma unroll
            for (int h = 0; h < 4; ++h) {
                float sh = agent_load(&S[i * 4 + h]);
                float ch = agent_load(&Cnt[i * 4 + h]);
                numr -= ch * (INVT + logf(sh));
                c += ch;
            }
            if (c > 0.f) { ls = -(numr / c); lc = 1.f; }
        }
#pragma unroll
        for (int off = 1; off < 64; off <<= 1) {
            ls += __shfl_xor(ls, off, 64);
            lc += __shfl_xor(lc, off, 64);
        }
        if (tid == 0) {
            atomicAdd(&red[0], ls);
            atomicAdd(&red[1], lc);
            __threadfence();
            if (atomicAdd(done, 1u) == 127u) {
                float s  = atomicAdd(&red[0], 0.0f);
                float cc = atomicAdd(&red[1], 0.0f);
                out[0] = s / cc;
            }
        }
    }
}

extern "C" void kernel_launch(void* const* d_in, const int* in_sizes, int n_in,
                              void* d_out, int out_size, void* d_ws, size_t ws_size,
                              hipStream_t stream) {
    const float* feat = (const float*)d_in[0];    // (2048, 2, 256) f32
    const float* labels = (const float*)d_in[1];  // (2048, 10) f32
    float* out = (float*)d_out;

    char* ws = (char*)d_ws;
    unsigned short* fnb = (unsigned short*)ws;                     // N*E bf16 (2 MB)
    float* S = (float*)(ws + (size_t)NROW * EDIM * sizeof(unsigned short));
    float* Num = S + NROW * 4;
    float* Cnt = Num + NROW;
    float* red = Cnt + NROW * 4;              // red[0]=sum, red[1]=count
    unsigned* done = (unsigned*)(red + 2);    // global completion counter
    unsigned* cnt_bx = done + 1;              // per-i-group contributor counters [128]
    unsigned* bits = cnt_bx + 128;            // BS label bitmasks

    prep_kernel<<<NROW + 8, 256, 0, stream>>>(feat, labels, fnb, bits, S);
    main_kernel<<<dim3(128, 8), 128, 0, stream>>>(fnb, bits, S, Num, Cnt, red, done, cnt_bx, out);
}